// Round 4
// baseline (384.896 us; speedup 1.0000x reference)
//
#include <hip/hip_runtime.h>
#include <hip/hip_bf16.h>

#define NB 2
#define NS 2048
#define NH 16
#define ND 64
#define NHID 1024

// exp(x/32) = exp2(x * log2(e)/32) ; folded into Wq/bq at conversion time
#define QSCALE 0.045084220f

typedef __attribute__((ext_vector_type(8))) short bf16x8;
typedef __attribute__((ext_vector_type(4))) short s16x4;
typedef __attribute__((ext_vector_type(4))) float f32x4;

typedef __attribute__((address_space(3))) unsigned int lds_u32;
typedef __attribute__((address_space(1))) unsigned int glb_u32;

__device__ inline void gl_lds16(const void* g, void* l) {
  __builtin_amdgcn_global_load_lds((const glb_u32*)g, (lds_u32*)l, 16, 0, 0);
}

__device__ inline short f2bf(float f) {
  __hip_bfloat16 h = __float2bfloat16(f);
  short s; __builtin_memcpy(&s, &h, 2); return s;
}

// per-lane bit of a wave-uniform 64-bit mask selects e or 0: one VALU op.
__device__ inline float selbit(float e, unsigned long long m) {
  float r;
  asm("v_cndmask_b32 %0, 0, %1, %2" : "=v"(r) : "v"(e), "s"(m));
  return r;
}

__device__ inline bf16x8 cvt8(const float* __restrict__ p) {
  float4 x = *(const float4*)p;
  float4 y = *(const float4*)(p + 4);
  bf16x8 r;
  r[0] = f2bf(x.x); r[1] = f2bf(x.y); r[2] = f2bf(x.z); r[3] = f2bf(x.w);
  r[4] = f2bf(y.x); r[5] = f2bf(y.y); r[6] = f2bf(y.z); r[7] = f2bf(y.w);
  return r;
}

// ---------------------------------------------------------------------------
// Kernel 0: prep = pack_mask into wave-shaped u64 words (blocks 0..511)
//           + weight cvt (blocks 512..1547)
// Mask word (b, qg, kt, mt, r): bit l(=qq*16+c) = mask[b][qg*16+c][kt*64+mt*16+qq*4+r]
// Coalesced mapping: lane = (q4=lane>>4, g4 offset=lane&15); a 16-lane group
// reads 1KB contiguous per row; q4 OR-combine via shfl_xor 16/32.
// ---------------------------------------------------------------------------
__global__ __launch_bounds__(256) void prep(
    const int* __restrict__ mask, unsigned long long* __restrict__ mp,
    const float* __restrict__ Wq, const float* __restrict__ Wk,
    const float* __restrict__ Wv, const float* __restrict__ Wo,
    short* __restrict__ Wq_b, short* __restrict__ Wk_b,
    short* __restrict__ Wv_b, short* __restrict__ Wo_b)
{
  if (blockIdx.x < 512) {
    int idx = blockIdx.x * 256 + threadIdx.x;     // 0..131071
    int lane = threadIdx.x & 63;
    int q4 = lane >> 4;                           // quarter of the 16 q-rows
    int g4 = ((idx >> 6) << 4) | (lane & 15);     // word-group 0..32767
    int mt = g4 & 3, kt = (g4 >> 2) & 31, qg = (g4 >> 7) & 127, b = g4 >> 14;
    unsigned long long wq[4] = {0ull, 0ull, 0ull, 0ull};
#pragma unroll
    for (int cc = 0; cc < 4; ++cc) {
      int c2 = q4 * 4 + cc;
      const int4* p = (const int4*)(mask +
          ((size_t)(b * NS + qg * 16 + c2) * NS) + kt * 64 + mt * 16);
#pragma unroll
      for (int qq2 = 0; qq2 < 4; ++qq2) {
        int4 v = p[qq2];
        int sh = qq2 * 16 + c2;
        wq[0] |= (unsigned long long)(v.x != 0) << sh;
        wq[1] |= (unsigned long long)(v.y != 0) << sh;
        wq[2] |= (unsigned long long)(v.z != 0) << sh;
        wq[3] |= (unsigned long long)(v.w != 0) << sh;
      }
    }
    // OR-combine the 4 q4-partners (lane ^16, ^32 — disjoint bits), write one r.
#pragma unroll
    for (int r = 0; r < 4; ++r) {
      wq[r] |= __shfl_xor(wq[r], 16);
      wq[r] |= __shfl_xor(wq[r], 32);
    }
    mp[(size_t)g4 * 4 + q4] = wq[q4];
  } else {
    int i = ((blockIdx.x - 512) * 256 + threadIdx.x) * 4;  // 0..1060860
    const float* src; short* dst; int off; float sc = 1.0f;
    if (i < 1048576)      { src = Wo; dst = Wo_b; off = i; }
    else {
      int j = i - 1048576;
      if (j < 4096)       { src = Wq; dst = Wq_b; off = j; sc = QSCALE; }
      else if (j < 8192)  { src = Wk; dst = Wk_b; off = j - 4096; }
      else                { src = Wv; dst = Wv_b; off = j - 8192; }
    }
    float4 v = *(const float4*)(src + off);
    s16x4 o;
    o[0] = f2bf(v.x * sc); o[1] = f2bf(v.y * sc);
    o[2] = f2bf(v.z * sc); o[3] = f2bf(v.w * sc);
    *(s16x4*)(dst + off) = o;
  }
}

// ---------------------------------------------------------------------------
// Kernel 1: Q,K projection. Block = 4 waves, wave = 1 token (16 heads).
// ---------------------------------------------------------------------------
__global__ __launch_bounds__(256) void qk_proj(
    const float* __restrict__ qin, const float* __restrict__ kin,
    const short* __restrict__ Wq_b, const float* __restrict__ bq,
    const short* __restrict__ Wk_b, const float* __restrict__ bk,
    short* __restrict__ Qws, short* __restrict__ Kws)
{
  __shared__ __align__(16) short ldsT[4][16][72];
  const int tid = threadIdx.x;
  const int w = tid >> 6, lane = tid & 63;
  const int c = lane & 15, qq = lane >> 4;
  const int t = blockIdx.x * 4 + w;         // b*S + s
  const int b = t >> 11, s = t & (NS - 1);
  const int aoff = (t * 16 + c) * 64 + qq * 8;
  const int row0 = lane >> 3, inner = lane & 7;

#pragma unroll
  for (int m = 0; m < 2; ++m) {
    const float* X  = (m == 0) ? qin  : kin;
    const short* W  = (m == 0) ? Wq_b : Wk_b;
    const float* bb = (m == 0) ? bq   : bk;
    short* dst      = (m == 0) ? Qws  : Kws;
    const float bsc = (m == 0) ? QSCALE : 1.0f;

    bf16x8 a0 = cvt8(X + aoff);
    bf16x8 a1 = cvt8(X + aoff + 32);

#pragma unroll
    for (int nt = 0; nt < 4; ++nt) {
      f32x4 z = {0.f, 0.f, 0.f, 0.f};
      const short* wp = W + (nt * 16 + c) * 64 + qq * 8;
      bf16x8 b0 = *(const bf16x8*)(wp);
      bf16x8 b1 = *(const bf16x8*)(wp + 32);
      z = __builtin_amdgcn_mfma_f32_16x16x32_bf16(a0, b0, z, 0, 0, 0);
      z = __builtin_amdgcn_mfma_f32_16x16x32_bf16(a1, b1, z, 0, 0, 0);
      float bias = bb[nt * 16 + c] * bsc;
#pragma unroll
      for (int r = 0; r < 4; ++r)           // C row = head = qq*4+r
        ldsT[w][qq * 4 + r][nt * 16 + c] = f2bf(z[r] + bias);
    }

    bf16x8 v0 = *(const bf16x8*)&ldsT[w][row0][inner * 8];
    bf16x8 v1 = *(const bf16x8*)&ldsT[w][row0 + 8][inner * 8];
    int bh0 = b * NH + row0, bh1 = b * NH + row0 + 8;
    *(bf16x8*)(dst + (bh0 * NS + s) * 64 + inner * 8) = v0;
    *(bf16x8*)(dst + (bh1 * NS + s) * 64 + inner * 8) = v1;
  }
}

// ---------------------------------------------------------------------------
// Kernel 1b: V projection + 64x64 transpose. Block = 4 waves, wave = 16 tokens.
// ---------------------------------------------------------------------------
__global__ __launch_bounds__(256) void vproj(
    const float* __restrict__ vin, const short* __restrict__ Wv_b,
    const float* __restrict__ bv, short* __restrict__ Vt)
{
  __shared__ __align__(16) short ldsVT[64][72];   // [d][token]
  const int tid = threadIdx.x;
  const int g = tid >> 6, lane = tid & 63;
  const int c = lane & 15, qq = lane >> 4;
  const int bh = blockIdx.x >> 5;
  const int stile = blockIdx.x & 31;
  const int b = bh >> 4, h = bh & 15;
  const int sb = stile * 64;

  bf16x8 wv[8];
  float bias[4];
#pragma unroll
  for (int nt = 0; nt < 4; ++nt) {
    const short* wp = Wv_b + (nt * 16 + c) * 64 + qq * 8;
    wv[nt * 2]     = *(const bf16x8*)(wp);
    wv[nt * 2 + 1] = *(const bf16x8*)(wp + 32);
    bias[nt] = bv[nt * 16 + c];
  }

  const float* ap = vin + ((size_t)((b * NS + sb + 16 * g + c) * 16 + h)) * 64 + qq * 8;
  bf16x8 a0 = cvt8(ap);
  bf16x8 a1 = cvt8(ap + 32);
#pragma unroll
  for (int nt = 0; nt < 4; ++nt) {
    f32x4 z = {0.f, 0.f, 0.f, 0.f};
    z = __builtin_amdgcn_mfma_f32_16x16x32_bf16(a0, wv[nt * 2], z, 0, 0, 0);
    z = __builtin_amdgcn_mfma_f32_16x16x32_bf16(a1, wv[nt * 2 + 1], z, 0, 0, 0);
    ushort4 u;
    u.x = (unsigned short)f2bf(z[0] + bias[nt]);
    u.y = (unsigned short)f2bf(z[1] + bias[nt]);
    u.z = (unsigned short)f2bf(z[2] + bias[nt]);
    u.w = (unsigned short)f2bf(z[3] + bias[nt]);
    *(ushort4*)&ldsVT[nt * 16 + c][16 * g + qq * 4] = u;   // token = 16g+qq*4+r
  }
  __syncthreads();

#pragma unroll
  for (int j = 0; j < 2; ++j) {
    int idx = tid + 256 * j;            // 0..511
    int d = idx >> 3, unit = idx & 7;
    bf16x8 o = *(const bf16x8*)&ldsVT[d][unit * 8];
    *(bf16x8*)(Vt + ((size_t)(bh * 64 + d)) * NS + sb + unit * 8) = o;
  }
}

// ---------------------------------------------------------------------------
// Kernel 3: flash attention, transposed-score formulation — DE-STAGED.
// K/V fragments read directly from global (L2-resident per XCD: bh -> XCD h%8,
// 4 bh x 512KB = 2MB working set in 4MB L2; fragments are fully-consumed 64B
// segments). No K/V LDS, no barriers at all. LDS = per-wave Ps only (8KB).
// ---------------------------------------------------------------------------
__global__ __launch_bounds__(256, 4) void attn(
    const short* __restrict__ Qws, const short* __restrict__ Kws,
    const short* __restrict__ Vt, const unsigned long long* __restrict__ Mp,
    short* __restrict__ AO)
{
  __shared__ __align__(16) short Ps[4][16][64];   // per-wave P^T, XOR-swizzled 8KB

  const int tid = threadIdx.x;
  const int w = tid >> 6, lane = tid & 63;
  const int c = lane & 15, qq = lane >> 4;
  const int bh = blockIdx.x & 31;                 // XCD swizzle (head-major)
  const int qtile = blockIdx.x >> 5;              // 0..31
  const int b = bh >> 4, h = bh & 15;
  const int qbase = qtile * 64 + w * 16;
  const int ca2 = (lane & 7) << 1;                // Ps swizzle term

  const short* Qp = Qws + (size_t)bh * (NS * 64);
  const short* Kp = Kws + (size_t)bh * (NS * 64);
  const short* Vp = Vt + (size_t)bh * (64 * NS);

  // wave-uniform mask base (readfirstlane makes w provably uniform -> s_load)
  const int wu = __builtin_amdgcn_readfirstlane(w);
  const unsigned long long* mbase =
      Mp + (size_t)(b * (NS / 16) + qtile * 4 + wu) * ((NS / 64) * 16);

  bf16x8 aq0, aq1;
  {
    const short* qp = Qp + (qbase + c) * 64 + qq * 8;
    aq0 = *(const bf16x8*)(qp);
    aq1 = *(const bf16x8*)(qp + 32);
  }

  float lsum = 0.f;
  f32x4 O[4];
#pragma unroll
  for (int dt = 0; dt < 4; ++dt) { f32x4 z = {0.f, 0.f, 0.f, 0.f}; O[dt] = z; }

  short* Pw = &Ps[w][c][0];
  const short* kfb = Kp + c * 64 + qq * 8;          // + (kt*64+mt*16)*64
  const short* vfb = Vp + (size_t)c * NS + qq * 8;  // + dt*16*NS + kt*64 + ks*32

  for (int kt = 0; kt < NS / 64; ++kt) {
    // K fragment loads (direct global, 64B-granule fully consumed)
    bf16x8 ak[4][2];
#pragma unroll
    for (int mt = 0; mt < 4; ++mt) {
      const short* kp = kfb + (kt * 64 + mt * 16) * 64;
      ak[mt][0] = *(const bf16x8*)(kp);
      ak[mt][1] = *(const bf16x8*)(kp + 32);
    }
    // V fragment loads — independent of QK, issue early to hide under softmax
    bf16x8 vf[2][4];
#pragma unroll
    for (int ks = 0; ks < 2; ++ks)
#pragma unroll
      for (int dt = 0; dt < 4; ++dt)
        vf[ks][dt] = *(const bf16x8*)(vfb + (size_t)(dt * 16) * NS + kt * 64 + ks * 32);

    unsigned long long mw[16];
#pragma unroll
    for (int i = 0; i < 16; ++i) mw[i] = mbase[(size_t)kt * 16 + i];

    f32x4 st[4];
#pragma unroll
    for (int mt = 0; mt < 4; ++mt) {
      f32x4 z = {0.f, 0.f, 0.f, 0.f};
      z = __builtin_amdgcn_mfma_f32_16x16x32_bf16(ak[mt][0], aq0, z, 0, 0, 0);
      z = __builtin_amdgcn_mfma_f32_16x16x32_bf16(ak[mt][1], aq1, z, 0, 0, 0);
      st[mt] = z;
    }

#pragma unroll
    for (int mt = 0; mt < 4; ++mt) {
      f32x4 s = st[mt];
      float e0 = selbit(__builtin_amdgcn_exp2f(s[0]), mw[mt * 4 + 0]);
      float e1 = selbit(__builtin_amdgcn_exp2f(s[1]), mw[mt * 4 + 1]);
      float e2 = selbit(__builtin_amdgcn_exp2f(s[2]), mw[mt * 4 + 2]);
      float e3 = selbit(__builtin_amdgcn_exp2f(s[3]), mw[mt * 4 + 3]);
      lsum += (e0 + e1) + (e2 + e3);
      ushort4 u;
      u.x = (unsigned short)f2bf(e0);
      u.y = (unsigned short)f2bf(e1);
      u.z = (unsigned short)f2bf(e2);
      u.w = (unsigned short)f2bf(e3);
      *(ushort4*)&Pw[((mt * 4 + qq) ^ ca2) << 2] = u;
    }

#pragma unroll
    for (int ks = 0; ks < 2; ++ks) {
      bf16x8 pf = *(const bf16x8*)&Pw[((ks * 8 + qq * 2) ^ ca2) << 2];
#pragma unroll
      for (int dt = 0; dt < 4; ++dt)
        O[dt] = __builtin_amdgcn_mfma_f32_16x16x32_bf16(vf[ks][dt], pf, O[dt], 0, 0, 0);
    }
  }

  {
    float v = lsum;
    v += __shfl_xor(v, 16);
    v += __shfl_xor(v, 32);
    lsum = 1.0f / fmaxf(v, 1e-30f);
  }

  const int row = qbase + c;
#pragma unroll
  for (int dt = 0; dt < 4; ++dt) {
    ushort4 u;
    u.x = (unsigned short)f2bf(O[dt][0] * lsum);
    u.y = (unsigned short)f2bf(O[dt][1] * lsum);
    u.z = (unsigned short)f2bf(O[dt][2] * lsum);
    u.w = (unsigned short)f2bf(O[dt][3] * lsum);
    *(ushort4*)(AO + ((size_t)(b * NS + row)) * NHID + h * 64 + dt * 16 + qq * 4) = u;
  }
}

// ---------------------------------------------------------------------------
// Kernel 4: output projection, m97-style staged GEMM.
// Tile 64 rows x 128 cols per block (grid 64x8 = 512 = 2 blocks/CU), BK=64.
// ---------------------------------------------------------------------------
__global__ __launch_bounds__(256, 2) void oproj(
    const short* __restrict__ X, const short* __restrict__ Wo_b,
    const float* __restrict__ bo, float* __restrict__ out)
{
  __shared__ __align__(16) short As[2][64][64];    // 16 KB
  __shared__ __align__(16) short Bs[2][128][64];   // 32 KB
  const int tid = threadIdx.x;
  const int w = tid >> 6, lane = tid & 63;
  const int c = lane & 15, qq = lane >> 4;
  const int rowbase = blockIdx.x * 64;             // 0..63 row tiles
  const int colbase = blockIdx.y * 128;            // 0..7 col tiles
  const int mh = w & 1, nh = w >> 1;               // wave quadrant

  const int srow = lane >> 3;
  const int sunit = (lane & 7) ^ srow;             // XOR swizzle (global side)

  auto stage = [&](int kb, int buf) {
#pragma unroll
    for (int i = 0; i < 6; ++i) {                  // 24 insts / 4 waves
      int t = w * 6 + i;
      if (t < 8) {                                 // A: 64 rows x 64 shorts
        const short* g = X + (size_t)(rowbase + t * 8 + srow) * NHID
                           + kb * 64 + sunit * 8;
        gl_lds16(g, &As[buf][0][0] + t * 512);
      } else {                                     // B: 128 rows x 64 shorts
        int j = t - 8;
        const short* g = Wo_b + (size_t)(colbase + j * 8 + srow) * NHID
                              + kb * 64 + sunit * 8;
        gl_lds16(g, &Bs[buf][0][0] + j * 512);
      }
    }
  };

  f32x4 acc[2][4];
#pragma unroll
  for (int mt = 0; mt < 2; ++mt)
#pragma unroll
    for (int nt = 0; nt < 4; ++nt) { f32x4 z = {0.f, 0.f, 0.f, 0.f}; acc[mt][nt] = z; }

  stage(0, 0);
  __syncthreads();

  for (int kb = 0; kb < NHID / 64; ++kb) {
    const int buf = kb & 1;
    if (kb < NHID / 64 - 1) stage(kb + 1, buf ^ 1);

    bf16x8 af[2][2];
#pragma unroll
    for (int mt = 0; mt < 2; ++mt) {
      const short* ap = &As[buf][mh * 32 + mt * 16 + c][0];
#pragma unroll
      for (int ks = 0; ks < 2; ++ks)
        af[mt][ks] = *(const bf16x8*)(ap + ((((ks << 2) + qq) ^ (c & 7)) << 3));
    }
#pragma unroll
    for (int nt = 0; nt < 4; ++nt) {
      const short* bp = &Bs[buf][nh * 64 + nt * 16 + c][0];
#pragma unroll
      for (int ks = 0; ks < 2; ++ks) {
        bf16x8 bf = *(const bf16x8*)(bp + ((((ks << 2) + qq) ^ (c & 7)) << 3));
#pragma unroll
        for (int mt = 0; mt < 2; ++mt)
          acc[mt][nt] = __builtin_amdgcn_mfma_f32_16x16x32_bf16(af[mt][ks], bf, acc[mt][nt], 0, 0, 0);
      }
    }

    __syncthreads();
  }

#pragma unroll
  for (int nt = 0; nt < 4; ++nt) {
    int col = colbase + nh * 64 + nt * 16 + c;
    float bias = bo[col];
#pragma unroll
    for (int mt = 0; mt < 2; ++mt) {
      int row = rowbase + mh * 32 + mt * 16 + qq * 4;
#pragma unroll
      for (int r = 0; r < 4; ++r)
        out[(size_t)(row + r) * NHID + col] = acc[mt][nt][r] + bias;
    }
  }
}

// ---------------------------------------------------------------------------
extern "C" void kernel_launch(void* const* d_in, const int* in_sizes, int n_in,
                              void* d_out, int out_size, void* d_ws, size_t ws_size,
                              hipStream_t stream) {
  const float* qin = (const float*)d_in[0];
  const float* kin = (const float*)d_in[1];
  const float* vin = (const float*)d_in[2];
  const int*  mask = (const int*)d_in[3];
  const float* Wq = (const float*)d_in[4];
  const float* bq = (const float*)d_in[5];
  const float* Wk = (const float*)d_in[6];
  const float* bk = (const float*)d_in[7];
  const float* Wv = (const float*)d_in[8];
  const float* bv = (const float*)d_in[9];
  const float* Wo = (const float*)d_in[10];
  const float* bo = (const float*)d_in[11];
  float* out = (float*)d_out;

  char* ws = (char*)d_ws;
  short* Qws = (short*)(ws);                           // 8 MB  [BH,S,64]
  short* Kws = (short*)(ws + (size_t)(8 << 20));       // 8 MB  [BH,S,64]
  short* Vt  = (short*)(ws + (size_t)(16 << 20));      // 8 MB  [BH,64,S]
  short* AO  = (short*)(ws + (size_t)(24 << 20));      // 8 MB  [B,S,HID]
  unsigned long long* Mp = (unsigned long long*)(ws + (size_t)(32 << 20)); // 1 MB packed mask
  short* Wo_b = (short*)(ws + (size_t)(33 << 20));     // 2 MB
  short* Wq_b = (short*)(ws + (size_t)(35 << 20));     // 8 KB
  short* Wk_b = (short*)(ws + (size_t)(35 << 20) + 8192);
  short* Wv_b = (short*)(ws + (size_t)(35 << 20) + 16384);

  prep<<<1548, 256, 0, stream>>>(mask, Mp, Wq, Wk, Wv, Wo, Wq_b, Wk_b, Wv_b, Wo_b);
  qk_proj<<<NB * NS / 4, 256, 0, stream>>>(qin, kin, Wq_b, bq, Wk_b, bk, Qws, Kws);
  vproj<<<(NB * NH) * (NS / 64), 256, 0, stream>>>(vin, Wv_b, bv, Vt);
  attn<<<(NB * NH) * (NS / 64), 256, 0, stream>>>(Qws, Kws, Vt, Mp, AO);
  oproj<<<dim3(64, 8), 256, 0, stream>>>(AO, Wo_b, bo, out);
}

// Round 7
// 210.352 us; speedup vs baseline: 1.8298x; 1.8298x over previous
//
#include <hip/hip_runtime.h>
#include <hip/hip_bf16.h>

#define NB 2
#define NS 2048
#define NH 16
#define ND 64
#define NHID 1024

// exp(x/32) = exp2(x * log2(e)/32) ; folded into Wq/bq at conversion time
#define QSCALE 0.045084220f

typedef __attribute__((ext_vector_type(8))) short bf16x8;
typedef __attribute__((ext_vector_type(4))) short s16x4;
typedef __attribute__((ext_vector_type(4))) float f32x4;

typedef __attribute__((address_space(3))) unsigned int lds_u32;
typedef __attribute__((address_space(1))) unsigned int glb_u32;

__device__ inline void gl_lds16(const void* g, void* l) {
  __builtin_amdgcn_global_load_lds((const glb_u32*)g, (lds_u32*)l, 16, 0, 0);
}

__device__ inline short f2bf(float f) {
  __hip_bfloat16 h = __float2bfloat16(f);
  short s; __builtin_memcpy(&s, &h, 2); return s;
}

// per-lane bit of a wave-uniform 64-bit mask selects e or 0: one VALU op.
__device__ inline float selbit(float e, unsigned long long m) {
  float r;
  asm("v_cndmask_b32 %0, 0, %1, %2" : "=v"(r) : "v"(e), "s"(m));
  return r;
}

__device__ inline bf16x8 cvt8(const float* __restrict__ p) {
  float4 x = *(const float4*)p;
  float4 y = *(const float4*)(p + 4);
  bf16x8 r;
  r[0] = f2bf(x.x); r[1] = f2bf(x.y); r[2] = f2bf(x.z); r[3] = f2bf(x.w);
  r[4] = f2bf(y.x); r[5] = f2bf(y.y); r[6] = f2bf(y.z); r[7] = f2bf(y.w);
  return r;
}

// ---------------------------------------------------------------------------
// Kernel 0: prep = pack_mask into wave-shaped u64 words (blocks 0..511)
//           + weight cvt (blocks 512..1547)
// Mask word (b, qg, kt, mt, r): bit l(=qq*16+c) = mask[b][qg*16+c][kt*64+mt*16+qq*4+r]
// Coalesced mapping: lane = (q4=lane>>4, g4 offset=lane&15); a 16-lane group
// reads 1KB contiguous per row; q4 OR-combine via shfl_xor 16/32.
// ---------------------------------------------------------------------------
__global__ __launch_bounds__(256) void prep(
    const int* __restrict__ mask, unsigned long long* __restrict__ mp,
    const float* __restrict__ Wq, const float* __restrict__ Wk,
    const float* __restrict__ Wv, const float* __restrict__ Wo,
    short* __restrict__ Wq_b, short* __restrict__ Wk_b,
    short* __restrict__ Wv_b, short* __restrict__ Wo_b)
{
  if (blockIdx.x < 512) {
    int idx = blockIdx.x * 256 + threadIdx.x;     // 0..131071
    int lane = threadIdx.x & 63;
    int q4 = lane >> 4;                           // quarter of the 16 q-rows
    int g4 = ((idx >> 6) << 4) | (lane & 15);     // word-group 0..32767
    int mt = g4 & 3, kt = (g4 >> 2) & 31, qg = (g4 >> 7) & 127, b = g4 >> 14;
    unsigned long long wq[4] = {0ull, 0ull, 0ull, 0ull};
#pragma unroll
    for (int cc = 0; cc < 4; ++cc) {
      int c2 = q4 * 4 + cc;
      const int4* p = (const int4*)(mask +
          ((size_t)(b * NS + qg * 16 + c2) * NS) + kt * 64 + mt * 16);
#pragma unroll
      for (int qq2 = 0; qq2 < 4; ++qq2) {
        int4 v = p[qq2];
        int sh = qq2 * 16 + c2;
        wq[0] |= (unsigned long long)(v.x != 0) << sh;
        wq[1] |= (unsigned long long)(v.y != 0) << sh;
        wq[2] |= (unsigned long long)(v.z != 0) << sh;
        wq[3] |= (unsigned long long)(v.w != 0) << sh;
      }
    }
    // OR-combine the 4 q4-partners (lane ^16, ^32 — disjoint bits), write one r.
#pragma unroll
    for (int r = 0; r < 4; ++r) {
      wq[r] |= __shfl_xor(wq[r], 16);
      wq[r] |= __shfl_xor(wq[r], 32);
    }
    mp[(size_t)g4 * 4 + q4] = wq[q4];
  } else {
    int i = ((blockIdx.x - 512) * 256 + threadIdx.x) * 4;  // 0..1060860
    const float* src; short* dst; int off; float sc = 1.0f;
    if (i < 1048576)      { src = Wo; dst = Wo_b; off = i; }
    else {
      int j = i - 1048576;
      if (j < 4096)       { src = Wq; dst = Wq_b; off = j; sc = QSCALE; }
      else if (j < 8192)  { src = Wk; dst = Wk_b; off = j - 4096; }
      else                { src = Wv; dst = Wv_b; off = j - 8192; }
    }
    float4 v = *(const float4*)(src + off);
    s16x4 o;
    o[0] = f2bf(v.x * sc); o[1] = f2bf(v.y * sc);
    o[2] = f2bf(v.z * sc); o[3] = f2bf(v.w * sc);
    *(s16x4*)(dst + off) = o;
  }
}

// ---------------------------------------------------------------------------
// Kernel 1: fused QKV projection. Blocks 0..1023: Q,K path (wave = 1 token,
// 16 heads). Blocks 1024..2047: V projection + 64x64 transpose (wave = 16
// tokens). Bodies byte-identical to the previously-passing qk_proj / vproj;
// one 9216B LDS buffer serves both paths (block-uniform branch).
// ---------------------------------------------------------------------------
__global__ __launch_bounds__(256) void qkv_proj(
    const float* __restrict__ qin, const float* __restrict__ kin,
    const float* __restrict__ vin,
    const short* __restrict__ Wq_b, const float* __restrict__ bq,
    const short* __restrict__ Wk_b, const float* __restrict__ bk,
    const short* __restrict__ Wv_b, const float* __restrict__ bv,
    short* __restrict__ Qws, short* __restrict__ Kws, short* __restrict__ Vt)
{
  __shared__ __align__(16) short lds[4][16][72];   // 9216 B, reused by both paths
  const int tid = threadIdx.x;

  if (blockIdx.x < NB * NS / 4) {
    // ---- Q,K projection path ----
    const int w = tid >> 6, lane = tid & 63;
    const int c = lane & 15, qq = lane >> 4;
    const int t = blockIdx.x * 4 + w;         // b*S + s
    const int b = t >> 11, s = t & (NS - 1);
    const int aoff = (t * 16 + c) * 64 + qq * 8;
    const int row0 = lane >> 3, inner = lane & 7;

#pragma unroll
    for (int m = 0; m < 2; ++m) {
      const float* X  = (m == 0) ? qin  : kin;
      const short* W  = (m == 0) ? Wq_b : Wk_b;
      const float* bb = (m == 0) ? bq   : bk;
      short* dst      = (m == 0) ? Qws  : Kws;
      const float bsc = (m == 0) ? QSCALE : 1.0f;

      bf16x8 a0 = cvt8(X + aoff);
      bf16x8 a1 = cvt8(X + aoff + 32);

#pragma unroll
      for (int nt = 0; nt < 4; ++nt) {
        f32x4 z = {0.f, 0.f, 0.f, 0.f};
        const short* wp = W + (nt * 16 + c) * 64 + qq * 8;
        bf16x8 b0 = *(const bf16x8*)(wp);
        bf16x8 b1 = *(const bf16x8*)(wp + 32);
        z = __builtin_amdgcn_mfma_f32_16x16x32_bf16(a0, b0, z, 0, 0, 0);
        z = __builtin_amdgcn_mfma_f32_16x16x32_bf16(a1, b1, z, 0, 0, 0);
        float bias = bb[nt * 16 + c] * bsc;
#pragma unroll
        for (int r = 0; r < 4; ++r)           // C row = head = qq*4+r
          lds[w][qq * 4 + r][nt * 16 + c] = f2bf(z[r] + bias);
      }

      bf16x8 v0 = *(const bf16x8*)&lds[w][row0][inner * 8];
      bf16x8 v1 = *(const bf16x8*)&lds[w][row0 + 8][inner * 8];
      int bh0 = b * NH + row0, bh1 = b * NH + row0 + 8;
      *(bf16x8*)(dst + (bh0 * NS + s) * 64 + inner * 8) = v0;
      *(bf16x8*)(dst + (bh1 * NS + s) * 64 + inner * 8) = v1;
    }
  } else {
    // ---- V projection + transpose path ----
    short (*ldsVT)[72] = (short (*)[72])lds;       // [64][72] view, 9216 B
    const int bid = blockIdx.x - NB * NS / 4;
    const int g = tid >> 6, lane = tid & 63;
    const int c = lane & 15, qq = lane >> 4;
    const int bh = bid >> 5;
    const int stile = bid & 31;
    const int b = bh >> 4, h = bh & 15;
    const int sb = stile * 64;

    bf16x8 wv[8];
    float bias[4];
#pragma unroll
    for (int nt = 0; nt < 4; ++nt) {
      const short* wp = Wv_b + (nt * 16 + c) * 64 + qq * 8;
      wv[nt * 2]     = *(const bf16x8*)(wp);
      wv[nt * 2 + 1] = *(const bf16x8*)(wp + 32);
      bias[nt] = bv[nt * 16 + c];
    }

    const float* ap = vin + ((size_t)((b * NS + sb + 16 * g + c) * 16 + h)) * 64 + qq * 8;
    bf16x8 a0 = cvt8(ap);
    bf16x8 a1 = cvt8(ap + 32);
#pragma unroll
    for (int nt = 0; nt < 4; ++nt) {
      f32x4 z = {0.f, 0.f, 0.f, 0.f};
      z = __builtin_amdgcn_mfma_f32_16x16x32_bf16(a0, wv[nt * 2], z, 0, 0, 0);
      z = __builtin_amdgcn_mfma_f32_16x16x32_bf16(a1, wv[nt * 2 + 1], z, 0, 0, 0);
      ushort4 u;
      u.x = (unsigned short)f2bf(z[0] + bias[nt]);
      u.y = (unsigned short)f2bf(z[1] + bias[nt]);
      u.z = (unsigned short)f2bf(z[2] + bias[nt]);
      u.w = (unsigned short)f2bf(z[3] + bias[nt]);
      *(ushort4*)&ldsVT[nt * 16 + c][16 * g + qq * 4] = u;   // token = 16g+qq*4+r
    }
    __syncthreads();

#pragma unroll
    for (int j = 0; j < 2; ++j) {
      int idx = tid + 256 * j;            // 0..511
      int d = idx >> 3, unit = idx & 7;
      bf16x8 o = *(const bf16x8*)&ldsVT[d][unit * 8];
      *(bf16x8*)(Vt + ((size_t)(bh * 64 + d)) * NS + sb + unit * 8) = o;
    }
  }
}

// ---------------------------------------------------------------------------
// Kernel 3: flash attention, transposed-score formulation (round-2 numerics,
// byte-exact). Q-tile 64 (wave = 16 q-rows), grid 1024. Scalar-mask u64 words
// + single cndmask/elem. Ps XOR-swizzled [4][16][64]. ONLY addition vs the
// verified-passing version: s_setprio(1) around the two MFMA clusters (T5).
// ---------------------------------------------------------------------------
__global__ __launch_bounds__(256, 4) void attn(
    const short* __restrict__ Qws, const short* __restrict__ Kws,
    const short* __restrict__ Vt, const unsigned long long* __restrict__ Mp,
    short* __restrict__ AO)
{
  __shared__ __align__(16) short Ks[2][64][64];   // staged K tile (swizzled)  16KB
  __shared__ __align__(16) short Vs[2][64][64];   // staged V tile (swizzled)  16KB
  __shared__ __align__(16) short Ps[4][16][64];   // per-wave P^T, XOR-swizzled 8KB

  const int tid = threadIdx.x;
  const int w = tid >> 6, lane = tid & 63;
  const int c = lane & 15, qq = lane >> 4;
  const int bh = blockIdx.x & 31;                 // XCD swizzle (head-major)
  const int qtile = blockIdx.x >> 5;              // 0..31
  const int b = bh >> 4, h = bh & 15;
  const int qbase = qtile * 64 + w * 16;
  const int ca2 = (lane & 7) << 1;                // Ps swizzle term

  const short* Qp = Qws + (size_t)bh * (NS * 64);
  const short* Kp = Kws + (size_t)bh * (NS * 64);
  const short* Vp = Vt + (size_t)bh * (64 * NS);

  // wave-uniform mask base (readfirstlane makes w provably uniform -> s_load)
  const int wu = __builtin_amdgcn_readfirstlane(w);
  const unsigned long long* mbase =
      Mp + (size_t)(b * (NS / 16) + qtile * 4 + wu) * ((NS / 64) * 16);

  bf16x8 aq0, aq1;
  {
    const short* qp = Qp + (qbase + c) * 64 + qq * 8;
    aq0 = *(const bf16x8*)(qp);
    aq1 = *(const bf16x8*)(qp + 32);
  }

  float lsum = 0.f;
  f32x4 O[4];
#pragma unroll
  for (int dt = 0; dt < 4; ++dt) { f32x4 z = {0.f, 0.f, 0.f, 0.f}; O[dt] = z; }

  short* Pw = &Ps[w][c][0];

  const int srow = lane >> 3;
  const int sunit = (lane & 7) ^ srow;
  auto stage = [&](int kt, int buf) {
#pragma unroll
    for (int i = 0; i < 2; ++i) {
      int j = w * 2 + i;
      const short* gk = Kp + ((size_t)(kt * 64 + j * 8 + srow)) * 64 + sunit * 8;
      gl_lds16(gk, &Ks[buf][0][0] + j * 512);
      const short* gv = Vp + ((size_t)(j * 8 + srow)) * NS + kt * 64 + sunit * 8;
      gl_lds16(gv, &Vs[buf][0][0] + j * 512);
    }
  };

  stage(0, 0);
  __syncthreads();

  for (int kt = 0; kt < NS / 64; ++kt) {
    const int buf = kt & 1;
    if (kt < NS / 64 - 1) stage(kt + 1, buf ^ 1);

    unsigned long long mw[16];
#pragma unroll
    for (int i = 0; i < 16; ++i) mw[i] = mbase[(size_t)kt * 16 + i];

    f32x4 st[4];
    __builtin_amdgcn_s_setprio(1);
#pragma unroll
    for (int mt = 0; mt < 4; ++mt) {
      const short* kb = &Ks[buf][mt * 16 + c][0];
      bf16x8 ak0 = *(const bf16x8*)(kb + ((qq ^ (c & 7)) << 3));
      bf16x8 ak1 = *(const bf16x8*)(kb + (((4 + qq) ^ (c & 7)) << 3));
      f32x4 z = {0.f, 0.f, 0.f, 0.f};
      z = __builtin_amdgcn_mfma_f32_16x16x32_bf16(ak0, aq0, z, 0, 0, 0);
      z = __builtin_amdgcn_mfma_f32_16x16x32_bf16(ak1, aq1, z, 0, 0, 0);
      st[mt] = z;
    }
    __builtin_amdgcn_s_setprio(0);

#pragma unroll
    for (int mt = 0; mt < 4; ++mt) {
      f32x4 s = st[mt];
      float e0 = selbit(__builtin_amdgcn_exp2f(s[0]), mw[mt * 4 + 0]);
      float e1 = selbit(__builtin_amdgcn_exp2f(s[1]), mw[mt * 4 + 1]);
      float e2 = selbit(__builtin_amdgcn_exp2f(s[2]), mw[mt * 4 + 2]);
      float e3 = selbit(__builtin_amdgcn_exp2f(s[3]), mw[mt * 4 + 3]);
      lsum += (e0 + e1) + (e2 + e3);
      ushort4 u;
      u.x = (unsigned short)f2bf(e0);
      u.y = (unsigned short)f2bf(e1);
      u.z = (unsigned short)f2bf(e2);
      u.w = (unsigned short)f2bf(e3);
      *(ushort4*)&Pw[((mt * 4 + qq) ^ ca2) << 2] = u;
    }

    __builtin_amdgcn_s_setprio(1);
#pragma unroll
    for (int ks = 0; ks < 2; ++ks) {
      bf16x8 pf = *(const bf16x8*)&Pw[((ks * 8 + qq * 2) ^ ca2) << 2];
#pragma unroll
      for (int dt = 0; dt < 4; ++dt) {
        const short* vb = &Vs[buf][dt * 16 + c][0];
        bf16x8 vf = *(const bf16x8*)(vb + ((((ks << 2) + qq) ^ (c & 7)) << 3));
        O[dt] = __builtin_amdgcn_mfma_f32_16x16x32_bf16(vf, pf, O[dt], 0, 0, 0);
      }
    }
    __builtin_amdgcn_s_setprio(0);

    __syncthreads();
  }

  {
    float v = lsum;
    v += __shfl_xor(v, 16);
    v += __shfl_xor(v, 32);
    lsum = 1.0f / fmaxf(v, 1e-30f);
  }

  const int row = qbase + c;
#pragma unroll
  for (int dt = 0; dt < 4; ++dt) {
    ushort4 u;
    u.x = (unsigned short)f2bf(O[dt][0] * lsum);
    u.y = (unsigned short)f2bf(O[dt][1] * lsum);
    u.z = (unsigned short)f2bf(O[dt][2] * lsum);
    u.w = (unsigned short)f2bf(O[dt][3] * lsum);
    *(ushort4*)(AO + ((size_t)(b * NS + row)) * NHID + h * 64 + dt * 16 + qq * 4) = u;
  }
}

// ---------------------------------------------------------------------------
// Kernel 4: output projection, m97-style staged GEMM.
// Tile 64 rows x 128 cols per block (grid 64x8 = 512), BK=64.
// launch_bounds (256,3): LDS 48KB x 3 = 144KB fits -> 3 blocks/CU.
// ---------------------------------------------------------------------------
__global__ __launch_bounds__(256, 3) void oproj(
    const short* __restrict__ X, const short* __restrict__ Wo_b,
    const float* __restrict__ bo, float* __restrict__ out)
{
  __shared__ __align__(16) short As[2][64][64];    // 16 KB
  __shared__ __align__(16) short Bs[2][128][64];   // 32 KB
  const int tid = threadIdx.x;
  const int w = tid >> 6, lane = tid & 63;
  const int c = lane & 15, qq = lane >> 4;
  const int rowbase = blockIdx.x * 64;             // 0..63 row tiles
  const int colbase = blockIdx.y * 128;            // 0..7 col tiles
  const int mh = w & 1, nh = w >> 1;               // wave quadrant

  const int srow = lane >> 3;
  const int sunit = (lane & 7) ^ srow;             // XOR swizzle (global side)

  auto stage = [&](int kb, int buf) {
#pragma unroll
    for (int i = 0; i < 6; ++i) {                  // 24 insts / 4 waves
      int t = w * 6 + i;
      if (t < 8) {                                 // A: 64 rows x 64 shorts
        const short* g = X + (size_t)(rowbase + t * 8 + srow) * NHID
                           + kb * 64 + sunit * 8;
        gl_lds16(g, &As[buf][0][0] + t * 512);
      } else {                                     // B: 128 rows x 64 shorts
        int j = t - 8;
        const short* g = Wo_b + (size_t)(colbase + j * 8 + srow) * NHID
                              + kb * 64 + sunit * 8;
        gl_lds16(g, &Bs[buf][0][0] + j * 512);
      }
    }
  };

  f32x4 acc[2][4];
#pragma unroll
  for (int mt = 0; mt < 2; ++mt)
#pragma unroll
    for (int nt = 0; nt < 4; ++nt) { f32x4 z = {0.f, 0.f, 0.f, 0.f}; acc[mt][nt] = z; }

  stage(0, 0);
  __syncthreads();

  for (int kb = 0; kb < NHID / 64; ++kb) {
    const int buf = kb & 1;
    if (kb < NHID / 64 - 1) stage(kb + 1, buf ^ 1);

    bf16x8 af[2][2];
#pragma unroll
    for (int mt = 0; mt < 2; ++mt) {
      const short* ap = &As[buf][mh * 32 + mt * 16 + c][0];
#pragma unroll
      for (int ks = 0; ks < 2; ++ks)
        af[mt][ks] = *(const bf16x8*)(ap + ((((ks << 2) + qq) ^ (c & 7)) << 3));
    }
#pragma unroll
    for (int nt = 0; nt < 4; ++nt) {
      const short* bp = &Bs[buf][nh * 64 + nt * 16 + c][0];
#pragma unroll
      for (int ks = 0; ks < 2; ++ks) {
        bf16x8 bf = *(const bf16x8*)(bp + ((((ks << 2) + qq) ^ (c & 7)) << 3));
#pragma unroll
        for (int mt = 0; mt < 2; ++mt)
          acc[mt][nt] = __builtin_amdgcn_mfma_f32_16x16x32_bf16(af[mt][ks], bf, acc[mt][nt], 0, 0, 0);
      }
    }

    __syncthreads();
  }

#pragma unroll
  for (int nt = 0; nt < 4; ++nt) {
    int col = colbase + nh * 64 + nt * 16 + c;
    float bias = bo[col];
#pragma unroll
    for (int mt = 0; mt < 2; ++mt) {
      int row = rowbase + mh * 32 + mt * 16 + qq * 4;
#pragma unroll
      for (int r = 0; r < 4; ++r)
        out[(size_t)(row + r) * NHID + col] = acc[mt][nt][r] + bias;
    }
  }
}

// ---------------------------------------------------------------------------
extern "C" void kernel_launch(void* const* d_in, const int* in_sizes, int n_in,
                              void* d_out, int out_size, void* d_ws, size_t ws_size,
                              hipStream_t stream) {
  const float* qin = (const float*)d_in[0];
  const float* kin = (const float*)d_in[1];
  const float* vin = (const float*)d_in[2];
  const int*  mask = (const int*)d_in[3];
  const float* Wq = (const float*)d_in[4];
  const float* bq = (const float*)d_in[5];
  const float* Wk = (const float*)d_in[6];
  const float* bk = (const float*)d_in[7];
  const float* Wv = (const float*)d_in[8];
  const float* bv = (const float*)d_in[9];
  const float* Wo = (const float*)d_in[10];
  const float* bo = (const float*)d_in[11];
  float* out = (float*)d_out;

  char* ws = (char*)d_ws;
  short* Qws = (short*)(ws);                           // 8 MB  [BH,S,64]
  short* Kws = (short*)(ws + (size_t)(8 << 20));       // 8 MB  [BH,S,64]
  short* Vt  = (short*)(ws + (size_t)(16 << 20));      // 8 MB  [BH,64,S]
  short* AO  = (short*)(ws + (size_t)(24 << 20));      // 8 MB  [B,S,HID]
  unsigned long long* Mp = (unsigned long long*)(ws + (size_t)(32 << 20)); // 1 MB packed mask
  short* Wo_b = (short*)(ws + (size_t)(33 << 20));     // 2 MB
  short* Wq_b = (short*)(ws + (size_t)(35 << 20));     // 8 KB
  short* Wk_b = (short*)(ws + (size_t)(35 << 20) + 8192);
  short* Wv_b = (short*)(ws + (size_t)(35 << 20) + 16384);

  prep<<<1548, 256, 0, stream>>>(mask, Mp, Wq, Wk, Wv, Wo, Wq_b, Wk_b, Wv_b, Wo_b);
  qkv_proj<<<NB * NS / 4 + (NB * NH) * (NS / 64), 256, 0, stream>>>(
      qin, kin, vin, Wq_b, bq, Wk_b, bk, Wv_b, bv, Qws, Kws, Vt);
  attn<<<(NB * NH) * (NS / 64), 256, 0, stream>>>(Qws, Kws, Vt, Mp, AO);
  oproj<<<dim3(64, 8), 256, 0, stream>>>(AO, Wo_b, bo, out);
}

// Round 8
// 206.691 us; speedup vs baseline: 1.8622x; 1.0177x over previous
//
#include <hip/hip_runtime.h>
#include <hip/hip_bf16.h>

#define NB 2
#define NS 2048
#define NH 16
#define ND 64
#define NHID 1024

// exp(x/32) = exp2(x * log2(e)/32) ; folded into Wq/bq at conversion time
#define QSCALE 0.045084220f

typedef __attribute__((ext_vector_type(8))) short bf16x8;
typedef __attribute__((ext_vector_type(4))) short s16x4;
typedef __attribute__((ext_vector_type(4))) float f32x4;

typedef __attribute__((address_space(3))) unsigned int lds_u32;
typedef __attribute__((address_space(1))) unsigned int glb_u32;

__device__ inline void gl_lds16(const void* g, void* l) {
  __builtin_amdgcn_global_load_lds((const glb_u32*)g, (lds_u32*)l, 16, 0, 0);
}

__device__ inline short f2bf(float f) {
  __hip_bfloat16 h = __float2bfloat16(f);
  short s; __builtin_memcpy(&s, &h, 2); return s;
}

// per-lane bit of a wave-uniform 64-bit mask selects e or 0: one VALU op.
__device__ inline float selbit(float e, unsigned long long m) {
  float r;
  asm("v_cndmask_b32 %0, 0, %1, %2" : "=v"(r) : "v"(e), "s"(m));
  return r;
}

__device__ inline bf16x8 cvt8(const float* __restrict__ p) {
  float4 x = *(const float4*)p;
  float4 y = *(const float4*)(p + 4);
  bf16x8 r;
  r[0] = f2bf(x.x); r[1] = f2bf(x.y); r[2] = f2bf(x.z); r[3] = f2bf(x.w);
  r[4] = f2bf(y.x); r[5] = f2bf(y.y); r[6] = f2bf(y.z); r[7] = f2bf(y.w);
  return r;
}

// ---------------------------------------------------------------------------
// Kernel 0: prep = pack_mask into wave-shaped u64 words (blocks 0..511)
//           + weight cvt (blocks 512..1547)
// Mask word (b, qg, kt, mt, r): bit l(=qq*16+c) = mask[b][qg*16+c][kt*64+mt*16+qq*4+r]
// Coalesced mapping: lane = (q4=lane>>4, g4 offset=lane&15); a 16-lane group
// reads 1KB contiguous per row; q4 OR-combine via shfl_xor 16/32.
// ---------------------------------------------------------------------------
__global__ __launch_bounds__(256) void prep(
    const int* __restrict__ mask, unsigned long long* __restrict__ mp,
    const float* __restrict__ Wq, const float* __restrict__ Wk,
    const float* __restrict__ Wv, const float* __restrict__ Wo,
    short* __restrict__ Wq_b, short* __restrict__ Wk_b,
    short* __restrict__ Wv_b, short* __restrict__ Wo_b)
{
  if (blockIdx.x < 512) {
    int idx = blockIdx.x * 256 + threadIdx.x;     // 0..131071
    int lane = threadIdx.x & 63;
    int q4 = lane >> 4;                           // quarter of the 16 q-rows
    int g4 = ((idx >> 6) << 4) | (lane & 15);     // word-group 0..32767
    int mt = g4 & 3, kt = (g4 >> 2) & 31, qg = (g4 >> 7) & 127, b = g4 >> 14;
    unsigned long long wq[4] = {0ull, 0ull, 0ull, 0ull};
#pragma unroll
    for (int cc = 0; cc < 4; ++cc) {
      int c2 = q4 * 4 + cc;
      const int4* p = (const int4*)(mask +
          ((size_t)(b * NS + qg * 16 + c2) * NS) + kt * 64 + mt * 16);
#pragma unroll
      for (int qq2 = 0; qq2 < 4; ++qq2) {
        int4 v = p[qq2];
        int sh = qq2 * 16 + c2;
        wq[0] |= (unsigned long long)(v.x != 0) << sh;
        wq[1] |= (unsigned long long)(v.y != 0) << sh;
        wq[2] |= (unsigned long long)(v.z != 0) << sh;
        wq[3] |= (unsigned long long)(v.w != 0) << sh;
      }
    }
    // OR-combine the 4 q4-partners (lane ^16, ^32 — disjoint bits), write one r.
#pragma unroll
    for (int r = 0; r < 4; ++r) {
      wq[r] |= __shfl_xor(wq[r], 16);
      wq[r] |= __shfl_xor(wq[r], 32);
    }
    mp[(size_t)g4 * 4 + q4] = wq[q4];
  } else {
    int i = ((blockIdx.x - 512) * 256 + threadIdx.x) * 4;  // 0..1060860
    const float* src; short* dst; int off; float sc = 1.0f;
    if (i < 1048576)      { src = Wo; dst = Wo_b; off = i; }
    else {
      int j = i - 1048576;
      if (j < 4096)       { src = Wq; dst = Wq_b; off = j; sc = QSCALE; }
      else if (j < 8192)  { src = Wk; dst = Wk_b; off = j - 4096; }
      else                { src = Wv; dst = Wv_b; off = j - 8192; }
    }
    float4 v = *(const float4*)(src + off);
    s16x4 o;
    o[0] = f2bf(v.x * sc); o[1] = f2bf(v.y * sc);
    o[2] = f2bf(v.z * sc); o[3] = f2bf(v.w * sc);
    *(s16x4*)(dst + off) = o;
  }
}

// ---------------------------------------------------------------------------
// Kernel 1: fused QKV projection. Blocks 0..1023: Q,K path (wave = 1 token,
// 16 heads). Blocks 1024..2047: V projection + 64x64 transpose (wave = 16
// tokens). One 9216B LDS buffer serves both paths (block-uniform branch).
// ---------------------------------------------------------------------------
__global__ __launch_bounds__(256) void qkv_proj(
    const float* __restrict__ qin, const float* __restrict__ kin,
    const float* __restrict__ vin,
    const short* __restrict__ Wq_b, const float* __restrict__ bq,
    const short* __restrict__ Wk_b, const float* __restrict__ bk,
    const short* __restrict__ Wv_b, const float* __restrict__ bv,
    short* __restrict__ Qws, short* __restrict__ Kws, short* __restrict__ Vt)
{
  __shared__ __align__(16) short lds[4][16][72];   // 9216 B, reused by both paths
  const int tid = threadIdx.x;

  if (blockIdx.x < NB * NS / 4) {
    // ---- Q,K projection path ----
    const int w = tid >> 6, lane = tid & 63;
    const int c = lane & 15, qq = lane >> 4;
    const int t = blockIdx.x * 4 + w;         // b*S + s
    const int b = t >> 11, s = t & (NS - 1);
    const int aoff = (t * 16 + c) * 64 + qq * 8;
    const int row0 = lane >> 3, inner = lane & 7;

#pragma unroll
    for (int m = 0; m < 2; ++m) {
      const float* X  = (m == 0) ? qin  : kin;
      const short* W  = (m == 0) ? Wq_b : Wk_b;
      const float* bb = (m == 0) ? bq   : bk;
      short* dst      = (m == 0) ? Qws  : Kws;
      const float bsc = (m == 0) ? QSCALE : 1.0f;

      bf16x8 a0 = cvt8(X + aoff);
      bf16x8 a1 = cvt8(X + aoff + 32);

#pragma unroll
      for (int nt = 0; nt < 4; ++nt) {
        f32x4 z = {0.f, 0.f, 0.f, 0.f};
        const short* wp = W + (nt * 16 + c) * 64 + qq * 8;
        bf16x8 b0 = *(const bf16x8*)(wp);
        bf16x8 b1 = *(const bf16x8*)(wp + 32);
        z = __builtin_amdgcn_mfma_f32_16x16x32_bf16(a0, b0, z, 0, 0, 0);
        z = __builtin_amdgcn_mfma_f32_16x16x32_bf16(a1, b1, z, 0, 0, 0);
        float bias = bb[nt * 16 + c] * bsc;
#pragma unroll
        for (int r = 0; r < 4; ++r)           // C row = head = qq*4+r
          lds[w][qq * 4 + r][nt * 16 + c] = f2bf(z[r] + bias);
      }

      bf16x8 v0 = *(const bf16x8*)&lds[w][row0][inner * 8];
      bf16x8 v1 = *(const bf16x8*)&lds[w][row0 + 8][inner * 8];
      int bh0 = b * NH + row0, bh1 = b * NH + row0 + 8;
      *(bf16x8*)(dst + (bh0 * NS + s) * 64 + inner * 8) = v0;
      *(bf16x8*)(dst + (bh1 * NS + s) * 64 + inner * 8) = v1;
    }
  } else {
    // ---- V projection + transpose path ----
    short (*ldsVT)[72] = (short (*)[72])lds;       // [64][72] view, 9216 B
    const int bid = blockIdx.x - NB * NS / 4;
    const int g = tid >> 6, lane = tid & 63;
    const int c = lane & 15, qq = lane >> 4;
    const int bh = bid >> 5;
    const int stile = bid & 31;
    const int b = bh >> 4, h = bh & 15;
    const int sb = stile * 64;

    bf16x8 wv[8];
    float bias[4];
#pragma unroll
    for (int nt = 0; nt < 4; ++nt) {
      const short* wp = Wv_b + (nt * 16 + c) * 64 + qq * 8;
      wv[nt * 2]     = *(const bf16x8*)(wp);
      wv[nt * 2 + 1] = *(const bf16x8*)(wp + 32);
      bias[nt] = bv[nt * 16 + c];
    }

    const float* ap = vin + ((size_t)((b * NS + sb + 16 * g + c) * 16 + h)) * 64 + qq * 8;
    bf16x8 a0 = cvt8(ap);
    bf16x8 a1 = cvt8(ap + 32);
#pragma unroll
    for (int nt = 0; nt < 4; ++nt) {
      f32x4 z = {0.f, 0.f, 0.f, 0.f};
      z = __builtin_amdgcn_mfma_f32_16x16x32_bf16(a0, wv[nt * 2], z, 0, 0, 0);
      z = __builtin_amdgcn_mfma_f32_16x16x32_bf16(a1, wv[nt * 2 + 1], z, 0, 0, 0);
      ushort4 u;
      u.x = (unsigned short)f2bf(z[0] + bias[nt]);
      u.y = (unsigned short)f2bf(z[1] + bias[nt]);
      u.z = (unsigned short)f2bf(z[2] + bias[nt]);
      u.w = (unsigned short)f2bf(z[3] + bias[nt]);
      *(ushort4*)&ldsVT[nt * 16 + c][16 * g + qq * 4] = u;   // token = 16g+qq*4+r
    }
    __syncthreads();

#pragma unroll
    for (int j = 0; j < 2; ++j) {
      int idx = tid + 256 * j;            // 0..511
      int d = idx >> 3, unit = idx & 7;
      bf16x8 o = *(const bf16x8*)&ldsVT[d][unit * 8];
      *(bf16x8*)(Vt + ((size_t)(bh * 64 + d)) * NS + sb + unit * 8) = o;
    }
  }
}

// ---------------------------------------------------------------------------
// Kernel 3: flash attention. nq=2 merge of the two passing structures:
// wave = 32 q-rows (round-0 nq indexing), scalar-u64 mask + XOR-swizzled Ps
// (round-2). K-frags and V-frags shared across the two q-halves -> ~40% fewer
// LDS ops per q-row; 32 MFMA per barrier. Block = 4 waves x 32 q = 128-q tile;
// grid 512 (2 blocks/CU). LDS 48KB: Ks 16 + Vs 16 + Ps[4][32][64] 16.
// ---------------------------------------------------------------------------
__global__ __launch_bounds__(256, 2) void attn(
    const short* __restrict__ Qws, const short* __restrict__ Kws,
    const short* __restrict__ Vt, const unsigned long long* __restrict__ Mp,
    short* __restrict__ AO)
{
  __shared__ __align__(16) short Ks[2][64][64];   // staged K tile (swizzled) 16KB
  __shared__ __align__(16) short Vs[2][64][64];   // staged V tile (swizzled) 16KB
  __shared__ __align__(16) short Ps[4][32][64];   // per-wave P^T, XOR-swizzled 16KB

  const int tid = threadIdx.x;
  const int w = tid >> 6, lane = tid & 63;
  const int c = lane & 15, qq = lane >> 4;
  const int bh = blockIdx.x & 31;                 // XCD swizzle (head-major)
  const int qtile = blockIdx.x >> 5;              // 0..15
  const int b = bh >> 4, h = bh & 15;
  const int qbase = qtile * 128 + w * 32;
  const int ca2 = (lane & 7) << 1;                // Ps swizzle term

  const short* Qp = Qws + (size_t)bh * (NS * 64);
  const short* Kp = Kws + (size_t)bh * (NS * 64);
  const short* Vp = Vt + (size_t)bh * (64 * NS);

  // wave-uniform mask bases: qg = qtile*8 + w*2 + nq (16-row groups)
  const int wu = __builtin_amdgcn_readfirstlane(w);
  const unsigned long long* mbase0 =
      Mp + (size_t)(b * (NS / 16) + qtile * 8 + wu * 2) * ((NS / 64) * 16);
  const unsigned long long* mbase1 = mbase0 + ((NS / 64) * 16);

  bf16x8 aq[2][2];
#pragma unroll
  for (int nq = 0; nq < 2; ++nq) {
    const short* qp = Qp + (qbase + nq * 16 + c) * 64 + qq * 8;
    aq[nq][0] = *(const bf16x8*)(qp);
    aq[nq][1] = *(const bf16x8*)(qp + 32);
  }

  float lsum[2] = {0.f, 0.f};
  f32x4 O[2][4];
#pragma unroll
  for (int nq = 0; nq < 2; ++nq)
#pragma unroll
    for (int dt = 0; dt < 4; ++dt) { f32x4 z = {0.f, 0.f, 0.f, 0.f}; O[nq][dt] = z; }

  const int srow = lane >> 3;
  const int sunit = (lane & 7) ^ srow;
  auto stage = [&](int kt, int buf) {
#pragma unroll
    for (int i = 0; i < 2; ++i) {
      int j = w * 2 + i;
      const short* gk = Kp + ((size_t)(kt * 64 + j * 8 + srow)) * 64 + sunit * 8;
      gl_lds16(gk, &Ks[buf][0][0] + j * 512);
      const short* gv = Vp + ((size_t)(j * 8 + srow)) * NS + kt * 64 + sunit * 8;
      gl_lds16(gv, &Vs[buf][0][0] + j * 512);
    }
  };

  stage(0, 0);
  __syncthreads();

  for (int kt = 0; kt < NS / 64; ++kt) {
    const int buf = kt & 1;
    if (kt < NS / 64 - 1) stage(kt + 1, buf ^ 1);

    // QK^T cluster: K-frags shared across the two q-halves
    f32x4 st[4][2];
    __builtin_amdgcn_s_setprio(1);
#pragma unroll
    for (int mt = 0; mt < 4; ++mt) {
      const short* kb = &Ks[buf][mt * 16 + c][0];
      bf16x8 ak0 = *(const bf16x8*)(kb + ((qq ^ (c & 7)) << 3));
      bf16x8 ak1 = *(const bf16x8*)(kb + (((4 + qq) ^ (c & 7)) << 3));
#pragma unroll
      for (int nq = 0; nq < 2; ++nq) {
        f32x4 z = {0.f, 0.f, 0.f, 0.f};
        z = __builtin_amdgcn_mfma_f32_16x16x32_bf16(ak0, aq[nq][0], z, 0, 0, 0);
        z = __builtin_amdgcn_mfma_f32_16x16x32_bf16(ak1, aq[nq][1], z, 0, 0, 0);
        st[mt][nq] = z;
      }
    }
    __builtin_amdgcn_s_setprio(0);

    // mask + exp + Ps write, per q-half (16 scalar u64 words each)
#pragma unroll
    for (int nq = 0; nq < 2; ++nq) {
      const unsigned long long* mb = (nq == 0) ? mbase0 : mbase1;
      unsigned long long mw[16];
#pragma unroll
      for (int i = 0; i < 16; ++i) mw[i] = mb[(size_t)kt * 16 + i];
      short* Pw = &Ps[w][nq * 16 + c][0];
#pragma unroll
      for (int mt = 0; mt < 4; ++mt) {
        f32x4 s = st[mt][nq];
        float e0 = selbit(__builtin_amdgcn_exp2f(s[0]), mw[mt * 4 + 0]);
        float e1 = selbit(__builtin_amdgcn_exp2f(s[1]), mw[mt * 4 + 1]);
        float e2 = selbit(__builtin_amdgcn_exp2f(s[2]), mw[mt * 4 + 2]);
        float e3 = selbit(__builtin_amdgcn_exp2f(s[3]), mw[mt * 4 + 3]);
        lsum[nq] += (e0 + e1) + (e2 + e3);
        ushort4 u;
        u.x = (unsigned short)f2bf(e0);
        u.y = (unsigned short)f2bf(e1);
        u.z = (unsigned short)f2bf(e2);
        u.w = (unsigned short)f2bf(e3);
        *(ushort4*)&Pw[((mt * 4 + qq) ^ ca2) << 2] = u;
      }
    }

    // PV cluster: V-frags shared across the two q-halves
    __builtin_amdgcn_s_setprio(1);
#pragma unroll
    for (int ks = 0; ks < 2; ++ks) {
      bf16x8 pf[2];
#pragma unroll
      for (int nq = 0; nq < 2; ++nq)
        pf[nq] = *(const bf16x8*)&Ps[w][nq * 16 + c][((ks * 8 + qq * 2) ^ ca2) << 2];
#pragma unroll
      for (int dt = 0; dt < 4; ++dt) {
        const short* vb = &Vs[buf][dt * 16 + c][0];
        bf16x8 vf = *(const bf16x8*)(vb + ((((ks << 2) + qq) ^ (c & 7)) << 3));
#pragma unroll
        for (int nq = 0; nq < 2; ++nq)
          O[nq][dt] = __builtin_amdgcn_mfma_f32_16x16x32_bf16(vf, pf[nq], O[nq][dt], 0, 0, 0);
      }
    }
    __builtin_amdgcn_s_setprio(0);

    __syncthreads();
  }

#pragma unroll
  for (int nq = 0; nq < 2; ++nq) {
    float v = lsum[nq];
    v += __shfl_xor(v, 16);
    v += __shfl_xor(v, 32);
    lsum[nq] = 1.0f / fmaxf(v, 1e-30f);
  }

#pragma unroll
  for (int nq = 0; nq < 2; ++nq) {
    int row = qbase + nq * 16 + c;
#pragma unroll
    for (int dt = 0; dt < 4; ++dt) {
      ushort4 u;
      u.x = (unsigned short)f2bf(O[nq][dt][0] * lsum[nq]);
      u.y = (unsigned short)f2bf(O[nq][dt][1] * lsum[nq]);
      u.z = (unsigned short)f2bf(O[nq][dt][2] * lsum[nq]);
      u.w = (unsigned short)f2bf(O[nq][dt][3] * lsum[nq]);
      *(ushort4*)(AO + ((size_t)(b * NS + row)) * NHID + h * 64 + dt * 16 + qq * 4) = u;
    }
  }
}

// ---------------------------------------------------------------------------
// Kernel 4: output projection, m97-style staged GEMM.
// Tile 64 rows x 128 cols per block (grid 64x8 = 512), BK=64.
// launch_bounds (256,3): LDS 48KB x 3 = 144KB fits -> 3 blocks/CU.
// ---------------------------------------------------------------------------
__global__ __launch_bounds__(256, 3) void oproj(
    const short* __restrict__ X, const short* __restrict__ Wo_b,
    const float* __restrict__ bo, float* __restrict__ out)
{
  __shared__ __align__(16) short As[2][64][64];    // 16 KB
  __shared__ __align__(16) short Bs[2][128][64];   // 32 KB
  const int tid = threadIdx.x;
  const int w = tid >> 6, lane = tid & 63;
  const int c = lane & 15, qq = lane >> 4;
  const int rowbase = blockIdx.x * 64;             // 0..63 row tiles
  const int colbase = blockIdx.y * 128;            // 0..7 col tiles
  const int mh = w & 1, nh = w >> 1;               // wave quadrant

  const int srow = lane >> 3;
  const int sunit = (lane & 7) ^ srow;             // XOR swizzle (global side)

  auto stage = [&](int kb, int buf) {
#pragma unroll
    for (int i = 0; i < 6; ++i) {                  // 24 insts / 4 waves
      int t = w * 6 + i;
      if (t < 8) {                                 // A: 64 rows x 64 shorts
        const short* g = X + (size_t)(rowbase + t * 8 + srow) * NHID
                           + kb * 64 + sunit * 8;
        gl_lds16(g, &As[buf][0][0] + t * 512);
      } else {                                     // B: 128 rows x 64 shorts
        int j = t - 8;
        const short* g = Wo_b + (size_t)(colbase + j * 8 + srow) * NHID
                              + kb * 64 + sunit * 8;
        gl_lds16(g, &Bs[buf][0][0] + j * 512);
      }
    }
  };

  f32x4 acc[2][4];
#pragma unroll
  for (int mt = 0; mt < 2; ++mt)
#pragma unroll
    for (int nt = 0; nt < 4; ++nt) { f32x4 z = {0.f, 0.f, 0.f, 0.f}; acc[mt][nt] = z; }

  stage(0, 0);
  __syncthreads();

  for (int kb = 0; kb < NHID / 64; ++kb) {
    const int buf = kb & 1;
    if (kb < NHID / 64 - 1) stage(kb + 1, buf ^ 1);

    bf16x8 af[2][2];
#pragma unroll
    for (int mt = 0; mt < 2; ++mt) {
      const short* ap = &As[buf][mh * 32 + mt * 16 + c][0];
#pragma unroll
      for (int ks = 0; ks < 2; ++ks)
        af[mt][ks] = *(const bf16x8*)(ap + ((((ks << 2) + qq) ^ (c & 7)) << 3));
    }
#pragma unroll
    for (int nt = 0; nt < 4; ++nt) {
      const short* bp = &Bs[buf][nh * 64 + nt * 16 + c][0];
#pragma unroll
      for (int ks = 0; ks < 2; ++ks) {
        bf16x8 bf = *(const bf16x8*)(bp + ((((ks << 2) + qq) ^ (c & 7)) << 3));
#pragma unroll
        for (int mt = 0; mt < 2; ++mt)
          acc[mt][nt] = __builtin_amdgcn_mfma_f32_16x16x32_bf16(af[mt][ks], bf, acc[mt][nt], 0, 0, 0);
      }
    }

    __syncthreads();
  }

#pragma unroll
  for (int nt = 0; nt < 4; ++nt) {
    int col = colbase + nh * 64 + nt * 16 + c;
    float bias = bo[col];
#pragma unroll
    for (int mt = 0; mt < 2; ++mt) {
      int row = rowbase + mh * 32 + mt * 16 + qq * 4;
#pragma unroll
      for (int r = 0; r < 4; ++r)
        out[(size_t)(row + r) * NHID + col] = acc[mt][nt][r] + bias;
    }
  }
}

// ---------------------------------------------------------------------------
extern "C" void kernel_launch(void* const* d_in, const int* in_sizes, int n_in,
                              void* d_out, int out_size, void* d_ws, size_t ws_size,
                              hipStream_t stream) {
  const float* qin = (const float*)d_in[0];
  const float* kin = (const float*)d_in[1];
  const float* vin = (const float*)d_in[2];
  const int*  mask = (const int*)d_in[3];
  const float* Wq = (const float*)d_in[4];
  const float* bq = (const float*)d_in[5];
  const float* Wk = (const float*)d_in[6];
  const float* bk = (const float*)d_in[7];
  const float* Wv = (const float*)d_in[8];
  const float* bv = (const float*)d_in[9];
  const float* Wo = (const float*)d_in[10];
  const float* bo = (const float*)d_in[11];
  float* out = (float*)d_out;

  char* ws = (char*)d_ws;
  short* Qws = (short*)(ws);                           // 8 MB  [BH,S,64]
  short* Kws = (short*)(ws + (size_t)(8 << 20));       // 8 MB  [BH,S,64]
  short* Vt  = (short*)(ws + (size_t)(16 << 20));      // 8 MB  [BH,64,S]
  short* AO  = (short*)(ws + (size_t)(24 << 20));      // 8 MB  [B,S,HID]
  unsigned long long* Mp = (unsigned long long*)(ws + (size_t)(32 << 20)); // 1 MB packed mask
  short* Wo_b = (short*)(ws + (size_t)(33 << 20));     // 2 MB
  short* Wq_b = (short*)(ws + (size_t)(35 << 20));     // 8 KB
  short* Wk_b = (short*)(ws + (size_t)(35 << 20) + 8192);
  short* Wv_b = (short*)(ws + (size_t)(35 << 20) + 16384);

  prep<<<1548, 256, 0, stream>>>(mask, Mp, Wq, Wk, Wv, Wo, Wq_b, Wk_b, Wv_b, Wo_b);
  qkv_proj<<<NB * NS / 4 + (NB * NH) * (NS / 64), 256, 0, stream>>>(
      qin, kin, vin, Wq_b, bq, Wk_b, bk, Wv_b, bv, Qws, Kws, Vt);
  attn<<<(NB * NH) * (NS / 128), 256, 0, stream>>>(Qws, Kws, Vt, Mp, AO);
  oproj<<<dim3(64, 8), 256, 0, stream>>>(AO, Wo_b, bo, out);
}